// Round 1
// baseline (215.763 us; speedup 1.0000x reference)
//
#include <hip/hip_runtime.h>
#include <math.h>

// Problem constants (B,S,D,P,C,V) = (64,128,2048,118,2,512)
#define NB 64
#define NS 128
#define ND 2048
#define NP 118
#define NC 2
#define NV 512

// Segment sizes in float4 units
constexpr int SEG0 = (NB * NS * ND) / 4;      // recon: 4,194,304
constexpr int SEG1 = (NB * NS * NV) / 4;      // kld:   1,048,576
constexpr int SEG2 = (NB * NS * NP * NC) / 4; // pts:     483,328
constexpr int SEG3 = (NB * NP * NC) / 4;      // best:      3,776
constexpr int TOTAL4 = SEG0 + SEG1 + SEG2 + SEG3;

__global__ __launch_bounds__(256) void cqloss_kernel(
    const float* __restrict__ zs, const float* __restrict__ rzs,
    const float* __restrict__ pts, const float* __restrict__ pts_gt,
    const float* __restrict__ qy,
    const float* __restrict__ best, const float* __restrict__ best_gt,
    const int* __restrict__ mapping, const int* __restrict__ vd,
    float* __restrict__ out)
{
    // weights folded into per-element scale
    const float w_recon = 1.0f / 16777216.0f;          // GAMMA / (B*S*D)
    const float w_kld   = 0.1f / 8192.0f;              // BETA / (B*S)
    const float w_disk  = 1.0f / 1933312.0f;           // 1 / (B*S*P*C)
    const float w_land  = 10.0f / 65536.0f;            // ALPHA / (B*S*4*C)
    const float w_best  = 1.0f / 15104.0f;             // 1 / (B*P*C)
    const float w_bland = 10.0f / 512.0f;              // ALPHA / (B*4*C)
    const float log_g   = -__logf((float)vd[0]);       // log(1/V)

    float acc = 0.0f;
    int tid = blockIdx.x * blockDim.x + threadIdx.x;
    int stride = gridDim.x * blockDim.x;

    for (int i = tid; i < TOTAL4; i += stride) {
        if (i < SEG0) {
            // recon: mse(rzs[b, m[b,s], :], zs[b, s, :])
            int base = i << 2;                 // flat elem index in [B,S,D]
            int b = base >> 18;                // / (S*D = 262144)
            int rem = base & (262143);
            int s = rem >> 11;                 // / D
            int d = rem & 2047;
            int m = mapping[(b << 7) + s];
            const float4 z = *(const float4*)(zs + base);
            const float4 r = *(const float4*)(rzs + ((((b << 7) + m) << 11) + d));
            float dx = r.x - z.x, dy = r.y - z.y, dz = r.z - z.z, dw = r.w - z.w;
            acc += w_recon * (dx * dx + dy * dy + dz * dz + dw * dw);
        } else if (i < SEG0 + SEG1) {
            // kld vs uniform
            int base = (i - SEG0) << 2;
            const float4 q = *(const float4*)(qy + base);
            acc += w_kld * (q.x * (__logf(q.x + 1e-20f) - log_g)
                          + q.y * (__logf(q.y + 1e-20f) - log_g)
                          + q.z * (__logf(q.z + 1e-20f) - log_g)
                          + q.w * (__logf(q.w + 1e-20f) - log_g));
        } else if (i < SEG0 + SEG1 + SEG2) {
            // pts: disk + ALPHA * landmark, gathered rows
            int k = i - (SEG0 + SEG1);
            int bs = k / 59;                   // slice = P*C/4 = 59 vec4
            int qo = k - bs * 59;
            int b = bs >> 7, s = bs & 127;
            int m = mapping[(b << 7) + s];
            int off = qo << 2;                 // elem offset within 236-slice
            const float4 x = *(const float4*)(pts + (b * NS + m) * 236 + off);
            const float4 g = *(const float4*)(pts_gt + bs * 236 + off);
            const float* xp = (const float*)&x;
            const float* gp = (const float*)&g;
            #pragma unroll
            for (int j = 0; j < 4; ++j) {
                int p = (off + j) >> 1;
                bool marked = (p == 0) | (p == 29) | (p == 88) | (p == 117);
                float w = w_disk + (marked ? w_land : 0.0f);
                float d = xp[j] - gp[j];
                acc += w * d * d;
            }
        } else {
            // best: full mse + ALPHA * landmark mse (no gather)
            int l = i - (SEG0 + SEG1 + SEG2);
            int b = l / 59;
            int qo = l - b * 59;
            int off = qo << 2;
            int base = b * 236 + off;
            const float4 x = *(const float4*)(best + base);
            const float4 g = *(const float4*)(best_gt + base);
            const float* xp = (const float*)&x;
            const float* gp = (const float*)&g;
            #pragma unroll
            for (int j = 0; j < 4; ++j) {
                int p = (off + j) >> 1;
                bool marked = (p == 0) | (p == 29) | (p == 88) | (p == 117);
                float w = w_best + (marked ? w_bland : 0.0f);
                float d = xp[j] - gp[j];
                acc += w * d * d;
            }
        }
    }

    // wave (64-lane) shuffle reduction
    #pragma unroll
    for (int o = 32; o > 0; o >>= 1) acc += __shfl_down(acc, o, 64);

    __shared__ float wsum[4]; // 256 threads / 64 lanes
    int lane = threadIdx.x & 63;
    int wave = threadIdx.x >> 6;
    if (lane == 0) wsum[wave] = acc;
    __syncthreads();
    if (threadIdx.x == 0) {
        float s = wsum[0] + wsum[1] + wsum[2] + wsum[3];
        atomicAdd(out, s);
    }
}

extern "C" void kernel_launch(void* const* d_in, const int* in_sizes, int n_in,
                              void* d_out, int out_size, void* d_ws, size_t ws_size,
                              hipStream_t stream) {
    const float* zs      = (const float*)d_in[0];
    const float* rzs     = (const float*)d_in[1];
    const float* pts     = (const float*)d_in[2];
    const float* pts_gt  = (const float*)d_in[3];
    const float* qy      = (const float*)d_in[4];
    // d_in[5] = logits: unused by the reference
    const float* best    = (const float*)d_in[6];
    const float* best_gt = (const float*)d_in[7];
    const int*   mapping = (const int*)d_in[8];
    const int*   vd      = (const int*)d_in[9];
    float* out = (float*)d_out;

    // d_out is re-poisoned (0xAA) before every timed replay — zero it on-stream.
    hipMemsetAsync(out, 0, sizeof(float), stream);

    cqloss_kernel<<<4096, 256, 0, stream>>>(zs, rzs, pts, pts_gt, qy,
                                            best, best_gt, mapping, vd, out);
}

// Round 2
// 214.914 us; speedup vs baseline: 1.0040x; 1.0040x over previous
//
#include <hip/hip_runtime.h>
#include <math.h>

// Problem constants (B,S,D,P,C,V) = (64,128,2048,118,2,512)
#define NB 64
#define NS 128
#define ND 2048
#define NP 118
#define NC 2
#define NV 512

// Segment sizes in float4 units
constexpr int SEG0 = (NB * NS * ND) / 4;      // recon: 4,194,304 vec4
constexpr int SEG1 = (NB * NS * NV) / 4;      // kld:   1,048,576 vec4
constexpr int SEG2 = (NB * NS * NP * NC) / 4; // pts:     483,328 vec4 (8192 rows x 59)
constexpr int SEG3 = (NB * NP * NC) / 4;      // best:      3,776 vec4

// Block partitioning (uniform control flow per block):
constexpr int RECON_BLOCKS = 4096;  // 2 rows (2*2048 floats) per block
constexpr int KLD_BLOCKS   = 512;   // 2048 vec4 per block
constexpr int PTS_BLOCKS   = 512;   // 16 rows (16*59=944 vec4) per block
constexpr int BEST_BLOCKS  = 16;    // 236 vec4 per block
constexpr int TOTAL_BLOCKS = RECON_BLOCKS + KLD_BLOCKS + PTS_BLOCKS + BEST_BLOCKS; // 5136

__global__ __launch_bounds__(256) void cqloss_kernel(
    const float* __restrict__ zs, const float* __restrict__ rzs,
    const float* __restrict__ pts, const float* __restrict__ pts_gt,
    const float* __restrict__ qy,
    const float* __restrict__ best, const float* __restrict__ best_gt,
    const int* __restrict__ mapping, const int* __restrict__ vd,
    float* __restrict__ out)
{
    const float w_recon = 1.0f / 16777216.0f;          // GAMMA / (B*S*D)
    const float w_kld   = 0.1f / 8192.0f;              // BETA / (B*S)
    const float w_disk  = 1.0f / 1933312.0f;           // 1 / (B*S*P*C)
    const float w_land  = 10.0f / 65536.0f;            // ALPHA / (B*S*4*C)
    const float w_best  = 1.0f / 15104.0f;             // 1 / (B*P*C)
    const float w_bland = 10.0f / 512.0f;              // ALPHA / (B*4*C)

    const int t   = threadIdx.x;
    const int blk = blockIdx.x;
    float acc = 0.0f;

    __shared__ int mrow[16];   // used by pts region only

    if (blk < RECON_BLOCKS) {
        // ---- recon: mse(rzs[b, m[b,s], :], zs[b, s, :]) — 2 rows per block
        const int row0 = blk << 1;
        // scalar (block-uniform) mapping loads for both rows
        const int m0 = mapping[row0];
        const int m1 = mapping[row0 + 1];
        const int b0 = row0 >> 7;
        const int b1 = (row0 + 1) >> 7;
        const float4* zp0 = (const float4*)(zs  + ((size_t)row0 << 11));
        const float4* zp1 = (const float4*)(zs  + ((size_t)(row0 + 1) << 11));
        const float4* rp0 = (const float4*)(rzs + ((size_t)((b0 << 7) + m0) << 11));
        const float4* rp1 = (const float4*)(rzs + ((size_t)((b1 << 7) + m1) << 11));
        // 8 independent float4 loads, issued before any use
        float4 za = zp0[t], zb = zp0[t + 256];
        float4 ra = rp0[t], rb = rp0[t + 256];
        float4 zc = zp1[t], zd = zp1[t + 256];
        float4 rc = rp1[t], rd = rp1[t + 256];
        float s = 0.0f;
        {
            float dx = ra.x - za.x, dy = ra.y - za.y, dz = ra.z - za.z, dw = ra.w - za.w;
            s += dx*dx + dy*dy + dz*dz + dw*dw;
        }
        {
            float dx = rb.x - zb.x, dy = rb.y - zb.y, dz = rb.z - zb.z, dw = rb.w - zb.w;
            s += dx*dx + dy*dy + dz*dz + dw*dw;
        }
        {
            float dx = rc.x - zc.x, dy = rc.y - zc.y, dz = rc.z - zc.z, dw = rc.w - zc.w;
            s += dx*dx + dy*dy + dz*dz + dw*dw;
        }
        {
            float dx = rd.x - zd.x, dy = rd.y - zd.y, dz = rd.z - zd.z, dw = rd.w - zd.w;
            s += dx*dx + dy*dy + dz*dz + dw*dw;
        }
        acc = w_recon * s;
    } else if (blk < RECON_BLOCKS + KLD_BLOCKS) {
        // ---- kld vs uniform: 2048 vec4 per block, 8 per thread
        const int rb = blk - RECON_BLOCKS;
        const float log_g = -__logf((float)vd[0]);     // log(1/V), scalar
        const float4* qp = (const float4*)qy + ((size_t)rb << 11) + t;
        float4 q[8];
        #pragma unroll
        for (int k = 0; k < 8; ++k) q[k] = qp[k * 256];
        float s = 0.0f;
        #pragma unroll
        for (int k = 0; k < 8; ++k) {
            s += q[k].x * (__logf(q[k].x + 1e-20f) - log_g)
               + q[k].y * (__logf(q[k].y + 1e-20f) - log_g)
               + q[k].z * (__logf(q[k].z + 1e-20f) - log_g)
               + q[k].w * (__logf(q[k].w + 1e-20f) - log_g);
        }
        acc = w_kld * s;
    } else if (blk < RECON_BLOCKS + KLD_BLOCKS + PTS_BLOCKS) {
        // ---- pts: disk + ALPHA*landmark over gathered rows; 16 rows per block
        const int rb = blk - (RECON_BLOCKS + KLD_BLOCKS);
        if (t < 16) mrow[t] = mapping[(rb << 4) + t];
        __syncthreads();
        const int bs_base = rb << 4;
        // w = t + j*256 covers 0..943 (16 rows x 59 vec4); j=0..2 always valid
        #pragma unroll
        for (int j = 0; j < 3; ++j) {
            const int w = t + j * 256;
            const unsigned rl = (unsigned)w / 59u;     // row_local 0..15
            const int qo = w - (int)rl * 59;           // vec4 offset in row
            const int bs = bs_base + (int)rl;
            const int b  = bs >> 7;
            const int m  = mrow[rl];
            const float4 x = *(const float4*)(pts    + ((size_t)((b << 7) + m) * 236 + (qo << 2)));
            const float4 g = *(const float4*)(pts_gt + ((size_t)(rb * 944 + w) << 2));
            const float* xp = (const float*)&x;
            const float* gp = (const float*)&g;
            const int p2 = qo << 1;
            #pragma unroll
            for (int jj = 0; jj < 4; ++jj) {
                const int p = p2 + (jj >> 1);
                const bool marked = (p == 0) | (p == 29) | (p == 88) | (p == 117);
                const float wgt = w_disk + (marked ? w_land : 0.0f);
                const float d = xp[jj] - gp[jj];
                acc += wgt * d * d;
            }
        }
        {   // j = 3 tail: w in [768, 944)
            const int w = t + 768;
            if (w < 944) {
                const unsigned rl = (unsigned)w / 59u;
                const int qo = w - (int)rl * 59;
                const int bs = bs_base + (int)rl;
                const int b  = bs >> 7;
                const int m  = mrow[rl];
                const float4 x = *(const float4*)(pts    + ((size_t)((b << 7) + m) * 236 + (qo << 2)));
                const float4 g = *(const float4*)(pts_gt + ((size_t)(rb * 944 + w) << 2));
                const float* xp = (const float*)&x;
                const float* gp = (const float*)&g;
                const int p2 = qo << 1;
                #pragma unroll
                for (int jj = 0; jj < 4; ++jj) {
                    const int p = p2 + (jj >> 1);
                    const bool marked = (p == 0) | (p == 29) | (p == 88) | (p == 117);
                    const float wgt = w_disk + (marked ? w_land : 0.0f);
                    const float d = xp[jj] - gp[jj];
                    acc += wgt * d * d;
                }
            }
        }
    } else {
        // ---- best: full mse + ALPHA*landmark, 236 vec4 per block
        const int db = blk - (RECON_BLOCKS + KLD_BLOCKS + PTS_BLOCKS);
        if (t < 236) {
            const int l = db * 236 + t;                // global vec4 index
            const unsigned bq = (unsigned)l / 59u;
            const int qo = l - (int)bq * 59;
            const float4 x = *(const float4*)(best    + ((size_t)l << 2));
            const float4 g = *(const float4*)(best_gt + ((size_t)l << 2));
            const float* xp = (const float*)&x;
            const float* gp = (const float*)&g;
            const int p2 = qo << 1;
            #pragma unroll
            for (int jj = 0; jj < 4; ++jj) {
                const int p = p2 + (jj >> 1);
                const bool marked = (p == 0) | (p == 29) | (p == 88) | (p == 117);
                const float wgt = w_best + (marked ? w_bland : 0.0f);
                const float d = xp[jj] - gp[jj];
                acc += wgt * d * d;
            }
        }
    }

    // wave (64-lane) shuffle reduction
    #pragma unroll
    for (int o = 32; o > 0; o >>= 1) acc += __shfl_down(acc, o, 64);

    __shared__ float wsum[4];
    const int lane = t & 63;
    const int wave = t >> 6;
    if (lane == 0) wsum[wave] = acc;
    __syncthreads();
    if (t == 0) {
        atomicAdd(out, wsum[0] + wsum[1] + wsum[2] + wsum[3]);
    }
}

extern "C" void kernel_launch(void* const* d_in, const int* in_sizes, int n_in,
                              void* d_out, int out_size, void* d_ws, size_t ws_size,
                              hipStream_t stream) {
    const float* zs      = (const float*)d_in[0];
    const float* rzs     = (const float*)d_in[1];
    const float* pts     = (const float*)d_in[2];
    const float* pts_gt  = (const float*)d_in[3];
    const float* qy      = (const float*)d_in[4];
    // d_in[5] = logits: unused by the reference
    const float* best    = (const float*)d_in[6];
    const float* best_gt = (const float*)d_in[7];
    const int*   mapping = (const int*)d_in[8];
    const int*   vd      = (const int*)d_in[9];
    float* out = (float*)d_out;

    // d_out is re-poisoned (0xAA) before every timed replay — zero it on-stream.
    hipMemsetAsync(out, 0, sizeof(float), stream);

    cqloss_kernel<<<TOTAL_BLOCKS, 256, 0, stream>>>(zs, rzs, pts, pts_gt, qy,
                                                    best, best_gt, mapping, vd, out);
}

// Round 3
// 190.188 us; speedup vs baseline: 1.1345x; 1.1300x over previous
//
#include <hip/hip_runtime.h>
#include <math.h>

// Problem constants (B,S,D,P,C,V) = (64,128,2048,118,2,512)
#define NB 64
#define NS 128
#define ND 2048
#define NP 118
#define NC 2
#define NV 512

// Block partitioning (uniform control flow per block):
constexpr int RECON_BLOCKS = 2048;  // 4 rows (4*2048 floats) per block
constexpr int KLD_BLOCKS   = 512;   // 2048 vec4 per block
constexpr int PTS_BLOCKS   = 512;   // 16 rows (16*59=944 vec4) per block
constexpr int BEST_BLOCKS  = 16;    // 236 vec4 per block
constexpr int TOTAL_BLOCKS = RECON_BLOCKS + KLD_BLOCKS + PTS_BLOCKS + BEST_BLOCKS; // 3088

__global__ __launch_bounds__(256) void cq_main(
    const float* __restrict__ zs, const float* __restrict__ rzs,
    const float* __restrict__ pts, const float* __restrict__ pts_gt,
    const float* __restrict__ qy,
    const float* __restrict__ best, const float* __restrict__ best_gt,
    const int* __restrict__ mapping, const int* __restrict__ vd,
    float* __restrict__ partials)
{
    const float w_recon = 1.0f / 16777216.0f;          // GAMMA / (B*S*D)
    const float w_kld   = 0.1f / 8192.0f;              // BETA / (B*S)
    const float w_disk  = 1.0f / 1933312.0f;           // 1 / (B*S*P*C)
    const float w_land  = 10.0f / 65536.0f;            // ALPHA / (B*S*4*C)
    const float w_best  = 1.0f / 15104.0f;             // 1 / (B*P*C)
    const float w_bland = 10.0f / 512.0f;              // ALPHA / (B*4*C)

    const int t   = threadIdx.x;
    const int blk = blockIdx.x;
    float acc = 0.0f;

    __shared__ int mrow[16];   // pts region only

    if (blk < RECON_BLOCKS) {
        // ---- recon: mse(rzs[b, m[b,s], :], zs[b, s, :]) — 4 rows per block
        const int r0 = blk << 2;            // first (b,s) row; 4-row group never crosses batch
        const int b  = r0 >> 7;
        const int m0 = mapping[r0];
        const int m1 = mapping[r0 + 1];
        const int m2 = mapping[r0 + 2];
        const int m3 = mapping[r0 + 3];
        const float4* zb4 = (const float4*)zs  + ((size_t)r0 << 9);   // 512 vec4 per row
        const float4* rz4 = (const float4*)rzs + ((size_t)b << 16);   // b * 128 * 512
        const int rowbase0 = m0 << 9, rowbase1 = m1 << 9, rowbase2 = m2 << 9, rowbase3 = m3 << 9;
        // Load ALL payload first — forces 16 outstanding float4 loads (64 VGPRs)
        float4 z[8], r[8];
        #pragma unroll
        for (int k = 0; k < 8; ++k) z[k] = zb4[t + (k << 8)];
        r[0] = rz4[rowbase0 + t];
        r[1] = rz4[rowbase0 + 256 + t];
        r[2] = rz4[rowbase1 + t];
        r[3] = rz4[rowbase1 + 256 + t];
        r[4] = rz4[rowbase2 + t];
        r[5] = rz4[rowbase2 + 256 + t];
        r[6] = rz4[rowbase3 + t];
        r[7] = rz4[rowbase3 + 256 + t];
        float s = 0.0f;
        #pragma unroll
        for (int k = 0; k < 8; ++k) {
            float dx = r[k].x - z[k].x, dy = r[k].y - z[k].y;
            float dz = r[k].z - z[k].z, dw = r[k].w - z[k].w;
            s += dx*dx + dy*dy + dz*dz + dw*dw;
        }
        acc = w_recon * s;
    } else if (blk < RECON_BLOCKS + KLD_BLOCKS) {
        // ---- kld vs uniform: 2048 vec4 per block, 8 per thread
        const int rb = blk - RECON_BLOCKS;
        const float log_g = -__logf((float)vd[0]);     // log(1/V), scalar
        const float4* qp = (const float4*)qy + ((size_t)rb << 11) + t;
        float4 q[8];
        #pragma unroll
        for (int k = 0; k < 8; ++k) q[k] = qp[k * 256];
        float s = 0.0f;
        #pragma unroll
        for (int k = 0; k < 8; ++k) {
            s += q[k].x * (__logf(q[k].x + 1e-20f) - log_g)
               + q[k].y * (__logf(q[k].y + 1e-20f) - log_g)
               + q[k].z * (__logf(q[k].z + 1e-20f) - log_g)
               + q[k].w * (__logf(q[k].w + 1e-20f) - log_g);
        }
        acc = w_kld * s;
    } else if (blk < RECON_BLOCKS + KLD_BLOCKS + PTS_BLOCKS) {
        // ---- pts: disk + ALPHA*landmark over gathered rows; 16 rows per block
        const int rb = blk - (RECON_BLOCKS + KLD_BLOCKS);
        if (t < 16) mrow[t] = mapping[(rb << 4) + t];
        __syncthreads();
        const int bs_base = rb << 4;
        float4 x[4], g[4];
        int pbase[4];
        #pragma unroll
        for (int j = 0; j < 4; ++j) {
            const int w = t + j * 256;
            const unsigned rl = (unsigned)w / 59u;     // row_local 0..15 (16 for OOB tail)
            const int qo = w - (int)rl * 59;
            const bool valid = (w < 944);
            const int rl_c = valid ? (int)rl : 0;
            const int bs = bs_base + rl_c;
            const int b  = bs >> 7;
            const int m  = mrow[rl_c];
            const size_t xi = (size_t)((b << 7) + m) * 236 + (qo << 2);
            const size_t gi = (size_t)(rb * 944 + w) << 2;
            pbase[j] = qo << 1;
            x[j] = valid ? *(const float4*)(pts    + xi) : make_float4(0,0,0,0);
            g[j] = valid ? *(const float4*)(pts_gt + gi) : make_float4(0,0,0,0);
            if (!valid) pbase[j] = -100;  // never matches a landmark
        }
        #pragma unroll
        for (int j = 0; j < 4; ++j) {
            const float* xp = (const float*)&x[j];
            const float* gp = (const float*)&g[j];
            #pragma unroll
            for (int jj = 0; jj < 4; ++jj) {
                const int p = pbase[j] + (jj >> 1);
                const bool marked = (p == 0) | (p == 29) | (p == 88) | (p == 117);
                const float wgt = w_disk + (marked ? w_land : 0.0f);
                const float d = xp[jj] - gp[jj];
                acc += wgt * d * d;
            }
        }
    } else {
        // ---- best: full mse + ALPHA*landmark, 236 vec4 per block
        const int db = blk - (RECON_BLOCKS + KLD_BLOCKS + PTS_BLOCKS);
        if (t < 236) {
            const int l = db * 236 + t;                // global vec4 index
            const unsigned bq = (unsigned)l / 59u;
            const int qo = l - (int)bq * 59;
            const float4 x = *(const float4*)(best    + ((size_t)l << 2));
            const float4 g = *(const float4*)(best_gt + ((size_t)l << 2));
            const float* xp = (const float*)&x;
            const float* gp = (const float*)&g;
            const int p2 = qo << 1;
            #pragma unroll
            for (int jj = 0; jj < 4; ++jj) {
                const int p = p2 + (jj >> 1);
                const bool marked = (p == 0) | (p == 29) | (p == 88) | (p == 117);
                const float wgt = w_best + (marked ? w_bland : 0.0f);
                const float d = xp[jj] - gp[jj];
                acc += wgt * d * d;
            }
        }
    }

    // wave (64-lane) shuffle reduction
    #pragma unroll
    for (int o = 32; o > 0; o >>= 1) acc += __shfl_down(acc, o, 64);

    __shared__ float wsum[4];
    const int lane = t & 63;
    const int wave = t >> 6;
    if (lane == 0) wsum[wave] = acc;
    __syncthreads();
    if (t == 0) partials[blk] = wsum[0] + wsum[1] + wsum[2] + wsum[3];
}

__global__ __launch_bounds__(256) void cq_reduce(
    const float* __restrict__ partials, float* __restrict__ out)
{
    const int t = threadIdx.x;
    float acc = 0.0f;
    for (int i = t; i < TOTAL_BLOCKS; i += 256) acc += partials[i];
    #pragma unroll
    for (int o = 32; o > 0; o >>= 1) acc += __shfl_down(acc, o, 64);
    __shared__ float wsum[4];
    if ((t & 63) == 0) wsum[t >> 6] = acc;
    __syncthreads();
    if (t == 0) out[0] = wsum[0] + wsum[1] + wsum[2] + wsum[3];
}

extern "C" void kernel_launch(void* const* d_in, const int* in_sizes, int n_in,
                              void* d_out, int out_size, void* d_ws, size_t ws_size,
                              hipStream_t stream) {
    const float* zs      = (const float*)d_in[0];
    const float* rzs     = (const float*)d_in[1];
    const float* pts     = (const float*)d_in[2];
    const float* pts_gt  = (const float*)d_in[3];
    const float* qy      = (const float*)d_in[4];
    // d_in[5] = logits: unused by the reference
    const float* best    = (const float*)d_in[6];
    const float* best_gt = (const float*)d_in[7];
    const int*   mapping = (const int*)d_in[8];
    const int*   vd      = (const int*)d_in[9];
    float* out      = (float*)d_out;
    float* partials = (float*)d_ws;   // TOTAL_BLOCKS floats — ws is re-poisoned, we overwrite fully

    cq_main<<<TOTAL_BLOCKS, 256, 0, stream>>>(zs, rzs, pts, pts_gt, qy,
                                              best, best_gt, mapping, vd, partials);
    cq_reduce<<<1, 256, 0, stream>>>(partials, out);
}

// Round 4
// 189.619 us; speedup vs baseline: 1.1379x; 1.0030x over previous
//
#include <hip/hip_runtime.h>
#include <math.h>

// Problem constants (B,S,D,P,C,V) = (64,128,2048,118,2,512)
#define NB 64
#define NS 128
#define ND 2048
#define NP 118
#define NC 2
#define NV 512

// Block partitioning (uniform control flow per block):
constexpr int RECON_BLOCKS = 2048;  // 4 rows (4*2048 floats) per block
constexpr int KLD_BLOCKS   = 512;   // 2048 vec4 per block
constexpr int PTS_BLOCKS   = 512;   // 16 rows (16*59=944 vec4) per block
constexpr int BEST_BLOCKS  = 16;    // 236 vec4 per block
constexpr int TOTAL_BLOCKS = RECON_BLOCKS + KLD_BLOCKS + PTS_BLOCKS + BEST_BLOCKS; // 3088

// Force the compiler to issue every load above this line before consuming any
// result below it: volatile asm with a memory clobber pins memory-op order.
#define LOAD_FENCE() asm volatile("" ::: "memory")

__global__ __launch_bounds__(256) void cq_main(
    const float* __restrict__ zs, const float* __restrict__ rzs,
    const float* __restrict__ pts, const float* __restrict__ pts_gt,
    const float* __restrict__ qy,
    const float* __restrict__ best, const float* __restrict__ best_gt,
    const int* __restrict__ mapping, const int* __restrict__ vd,
    float* __restrict__ partials)
{
    const float w_recon = 1.0f / 16777216.0f;          // GAMMA / (B*S*D)
    const float w_kld   = 0.1f / 8192.0f;              // BETA / (B*S)
    const float w_disk  = 1.0f / 1933312.0f;           // 1 / (B*S*P*C)
    const float w_land  = 10.0f / 65536.0f;            // ALPHA / (B*S*4*C)
    const float w_best  = 1.0f / 15104.0f;             // 1 / (B*P*C)
    const float w_bland = 10.0f / 512.0f;              // ALPHA / (B*4*C)

    const int t   = threadIdx.x;
    const int blk = blockIdx.x;
    float acc = 0.0f;

    __shared__ int mrow[16];   // pts region only

    if (blk < RECON_BLOCKS) {
        // ---- recon: mse(rzs[b, m[b,s], :], zs[b, s, :]) — 4 rows per block
        const int r0 = blk << 2;            // 4-row group never crosses batch
        const int b  = r0 >> 7;
        const int m0 = mapping[r0];
        const int m1 = mapping[r0 + 1];
        const int m2 = mapping[r0 + 2];
        const int m3 = mapping[r0 + 3];
        const float4* zb4 = (const float4*)zs  + ((size_t)r0 << 9);   // 512 vec4 per row
        const float4* rz4 = (const float4*)rzs + ((size_t)b << 16);   // b * 128 * 512
        const int rb0 = m0 << 9, rb1 = m1 << 9, rb2 = m2 << 9, rb3 = m3 << 9;

        // Phase 1: issue ALL 16 loads (64 VGPRs of payload held live)
        float4 z[8], r[8];
        #pragma unroll
        for (int k = 0; k < 8; ++k) z[k] = zb4[t + (k << 8)];
        r[0] = rz4[rb0 + t];       r[1] = rz4[rb0 + 256 + t];
        r[2] = rz4[rb1 + t];       r[3] = rz4[rb1 + 256 + t];
        r[4] = rz4[rb2 + t];       r[5] = rz4[rb2 + 256 + t];
        r[6] = rz4[rb3 + t];       r[7] = rz4[rb3 + 256 + t];
        LOAD_FENCE();

        // Phase 2: consume
        float s = 0.0f;
        #pragma unroll
        for (int k = 0; k < 8; ++k) {
            float dx = r[k].x - z[k].x, dy = r[k].y - z[k].y;
            float dz = r[k].z - z[k].z, dw = r[k].w - z[k].w;
            s += dx*dx + dy*dy + dz*dz + dw*dw;
        }
        acc = w_recon * s;
    } else if (blk < RECON_BLOCKS + KLD_BLOCKS) {
        // ---- kld vs uniform: 2048 vec4 per block, 8 per thread
        const int rb = blk - RECON_BLOCKS;
        const float log_g = -__logf((float)vd[0]);     // log(1/V), scalar
        const float4* qp = (const float4*)qy + ((size_t)rb << 11) + t;
        float4 q[8];
        #pragma unroll
        for (int k = 0; k < 8; ++k) q[k] = qp[k * 256];
        LOAD_FENCE();
        float s = 0.0f;
        #pragma unroll
        for (int k = 0; k < 8; ++k) {
            s += q[k].x * (__logf(q[k].x + 1e-20f) - log_g)
               + q[k].y * (__logf(q[k].y + 1e-20f) - log_g)
               + q[k].z * (__logf(q[k].z + 1e-20f) - log_g)
               + q[k].w * (__logf(q[k].w + 1e-20f) - log_g);
        }
        acc = w_kld * s;
    } else if (blk < RECON_BLOCKS + KLD_BLOCKS + PTS_BLOCKS) {
        // ---- pts: disk + ALPHA*landmark over gathered rows; 16 rows per block
        const int rb = blk - (RECON_BLOCKS + KLD_BLOCKS);
        if (t < 16) mrow[t] = mapping[(rb << 4) + t];
        __syncthreads();
        const int bs_base = rb << 4;
        float4 x[4], g[4];
        int pbase[4];
        #pragma unroll
        for (int j = 0; j < 4; ++j) {
            const int w = t + j * 256;
            const unsigned rl = (unsigned)w / 59u;     // row_local
            const int qo = w - (int)rl * 59;
            const bool valid = (w < 944);
            const int rl_c = valid ? (int)rl : 0;
            const int bs = bs_base + rl_c;
            const int b  = bs >> 7;
            const int m  = mrow[rl_c];
            const size_t xi = (size_t)((b << 7) + m) * 236 + (qo << 2);
            const size_t gi = (size_t)(rb * 944 + w) << 2;
            pbase[j] = valid ? (qo << 1) : -100;
            x[j] = valid ? *(const float4*)(pts    + xi) : make_float4(0,0,0,0);
            g[j] = valid ? *(const float4*)(pts_gt + gi) : make_float4(0,0,0,0);
        }
        LOAD_FENCE();
        #pragma unroll
        for (int j = 0; j < 4; ++j) {
            const float* xp = (const float*)&x[j];
            const float* gp = (const float*)&g[j];
            #pragma unroll
            for (int jj = 0; jj < 4; ++jj) {
                const int p = pbase[j] + (jj >> 1);
                const bool marked = (p == 0) | (p == 29) | (p == 88) | (p == 117);
                const float wgt = w_disk + (marked ? w_land : 0.0f);
                const float d = xp[jj] - gp[jj];
                acc += wgt * d * d;
            }
        }
    } else {
        // ---- best: full mse + ALPHA*landmark, 236 vec4 per block
        const int db = blk - (RECON_BLOCKS + KLD_BLOCKS + PTS_BLOCKS);
        if (t < 236) {
            const int l = db * 236 + t;                // global vec4 index
            const unsigned bq = (unsigned)l / 59u;
            const int qo = l - (int)bq * 59;
            const float4 x = *(const float4*)(best    + ((size_t)l << 2));
            const float4 g = *(const float4*)(best_gt + ((size_t)l << 2));
            const float* xp = (const float*)&x;
            const float* gp = (const float*)&g;
            const int p2 = qo << 1;
            #pragma unroll
            for (int jj = 0; jj < 4; ++jj) {
                const int p = p2 + (jj >> 1);
                const bool marked = (p == 0) | (p == 29) | (p == 88) | (p == 117);
                const float wgt = w_best + (marked ? w_bland : 0.0f);
                const float d = xp[jj] - gp[jj];
                acc += wgt * d * d;
            }
        }
    }

    // wave (64-lane) shuffle reduction
    #pragma unroll
    for (int o = 32; o > 0; o >>= 1) acc += __shfl_down(acc, o, 64);

    __shared__ float wsum[4];
    const int lane = t & 63;
    const int wave = t >> 6;
    if (lane == 0) wsum[wave] = acc;
    __syncthreads();
    if (t == 0) partials[blk] = wsum[0] + wsum[1] + wsum[2] + wsum[3];
}

__global__ __launch_bounds__(256) void cq_reduce(
    const float* __restrict__ partials, float* __restrict__ out)
{
    const int t = threadIdx.x;
    float acc = 0.0f;
    for (int i = t; i < TOTAL_BLOCKS; i += 256) acc += partials[i];
    #pragma unroll
    for (int o = 32; o > 0; o >>= 1) acc += __shfl_down(acc, o, 64);
    __shared__ float wsum[4];
    if ((t & 63) == 0) wsum[t >> 6] = acc;
    __syncthreads();
    if (t == 0) out[0] = wsum[0] + wsum[1] + wsum[2] + wsum[3];
}

extern "C" void kernel_launch(void* const* d_in, const int* in_sizes, int n_in,
                              void* d_out, int out_size, void* d_ws, size_t ws_size,
                              hipStream_t stream) {
    const float* zs      = (const float*)d_in[0];
    const float* rzs     = (const float*)d_in[1];
    const float* pts     = (const float*)d_in[2];
    const float* pts_gt  = (const float*)d_in[3];
    const float* qy      = (const float*)d_in[4];
    // d_in[5] = logits: unused by the reference
    const float* best    = (const float*)d_in[6];
    const float* best_gt = (const float*)d_in[7];
    const int*   mapping = (const int*)d_in[8];
    const int*   vd      = (const int*)d_in[9];
    float* out      = (float*)d_out;
    float* partials = (float*)d_ws;   // TOTAL_BLOCKS floats — fully overwritten each call

    cq_main<<<TOTAL_BLOCKS, 256, 0, stream>>>(zs, rzs, pts, pts_gt, qy,
                                              best, best_gt, mapping, vd, partials);
    cq_reduce<<<1, 256, 0, stream>>>(partials, out);
}